// Round 1
// baseline (353.215 us; speedup 1.0000x reference)
//
#include <hip/hip_runtime.h>
#include <hip/hip_bf16.h>

typedef __bf16 bf16;
typedef __bf16 bf16x8 __attribute__((ext_vector_type(8)));
typedef float  f32x4  __attribute__((ext_vector_type(4)));

#define AS1 __attribute__((address_space(1)))
#define AS3 __attribute__((address_space(3)))

// 16B async global->LDS. LDS dest is wave-uniform base + lane*16 (pass the
// per-lane pointer; lane 0's address is the base).
__device__ __forceinline__ void load16_to_lds(const bf16* g, bf16* l) {
    __builtin_amdgcn_global_load_lds((const AS1 unsigned int*)g,
                                     (AS3 unsigned int*)l, 16, 0, 0);
}

// ---------------------------------------------------------------------------
// prep_w: conv_w fp32 [o][1024] -> bf16, same layout (A-operand is [o][k]).
__global__ __launch_bounds__(256) void prep_w(const float* __restrict__ w,
                                              bf16* __restrict__ wb) {
    int i = blockIdx.x * 256 + threadIdx.x;   // grid 1024 -> 262144 elems
    wb[i] = (bf16)w[i];
}

// ---------------------------------------------------------------------------
// pass0: read x (B,C,H,W) fp32 once.
//  - write x_t bf16: [m = b*16384 + h*128 + w][c 0..255]   (GEMM1 B-operand)
//  - write cT  bf16: [mc = b*4096 + j*64 + k][d*256 + c]   (GEMM2 B-operand)
// Block = (b, coarse row j, w-tile of 32 fine cols). 256 threads.
__global__ __launch_bounds__(256) void pass0(const float* __restrict__ x,
                                             bf16* __restrict__ xt,
                                             bf16* __restrict__ cT) {
    __shared__ bf16 tile[64 * 264];           // [pos = delta*32 + w][c], pad 264
    const int bid = blockIdx.x;               // grid 2048
    const int wt = bid & 3, j = (bid >> 2) & 63, b = bid >> 8;
    const int t = threadIdx.x;
    const int w0 = wt * 32;

    // load 256c x 2rows x 32w fp32 -> bf16 LDS (transposed to [pos][c])
    for (int i = 0; i < 16; ++i) {
        int g = i * 256 + t;                  // 4096 float4 chunks
        int c = g >> 4;
        int rem = g & 15;
        int dlt = rem >> 3, w4 = rem & 7;
        const float4 v = *(const float4*)(x +
            ((((size_t)b * 256 + c) * 128 + (2 * j + dlt)) * 128 + w0 + w4 * 4));
        int pos = dlt * 32 + w4 * 4;
        tile[(pos + 0) * 264 + c] = (bf16)v.x;
        tile[(pos + 1) * 264 + c] = (bf16)v.y;
        tile[(pos + 2) * 264 + c] = (bf16)v.z;
        tile[(pos + 3) * 264 + c] = (bf16)v.w;
    }
    __syncthreads();

    // x_t: 64 pos * 32 chunks of 16B, lanes along c -> contiguous 512B stores
    for (int i = 0; i < 8; ++i) {
        int q = i * 256 + t;
        int cq = q & 31, pos = q >> 5;
        int dlt = pos >> 5, w = pos & 31;
        bf16x8 v = *(const bf16x8*)&tile[pos * 264 + cq * 8];
        int h = 2 * j + dlt, wg = w0 + w;
        *(bf16x8*)(xt + (((size_t)b * 16384 + h * 128 + wg) * 256 + cq * 8)) = v;
    }

    // Haar: 16 coarse cols * 32 c-chunks
    for (int i = 0; i < 2; ++i) {
        int q = i * 256 + t;
        int cq = q & 31, kc = q >> 5;
        bf16x8 vp = *(const bf16x8*)&tile[(2 * kc) * 264 + cq * 8];
        bf16x8 vq = *(const bf16x8*)&tile[(2 * kc + 1) * 264 + cq * 8];
        bf16x8 vr = *(const bf16x8*)&tile[(32 + 2 * kc) * 264 + cq * 8];
        bf16x8 vs = *(const bf16x8*)&tile[(33 + 2 * kc) * 264 + cq * 8];
        bf16x8 oh, ov, od;
        #pragma unroll
        for (int e = 0; e < 8; ++e) {
            float p = (float)vp[e], qq = (float)vq[e];
            float r = (float)vr[e], s = (float)vs[e];
            oh[e] = (bf16)(0.5f * (p + qq - r - s));
            ov[e] = (bf16)(0.5f * (p - qq + r - s));
            od[e] = (bf16)(0.5f * (p - qq - r + s));
        }
        size_t row = ((size_t)b * 4096 + j * 64 + wt * 16 + kc) * 768;
        *(bf16x8*)(cT + row + 0 * 256 + cq * 8) = oh;
        *(bf16x8*)(cT + row + 1 * 256 + cq * 8) = ov;
        *(bf16x8*)(cT + row + 2 * 256 + cq * 8) = od;
    }
}

// ---------------------------------------------------------------------------
// gemm_bt: C[o][m] = sum_k W[o][kofs+k] * X[m][k].  m97-style 128x128 tile,
// BK=32, 4 waves each 64x64, 16x16x32 bf16 MFMA, global_load_lds staging.
// Output Y layout [b][o(256)][m & (Mplane-1)], Mplane = 1<<mshift.
__global__ __launch_bounds__(256) void gemm_bt(const bf16* __restrict__ W,
                                               const bf16* __restrict__ X,
                                               bf16* __restrict__ Y,
                                               int K, int kofs, int mshift) {
    __shared__ bf16 Wt[128 * 32];
    __shared__ bf16 Xt[128 * 32];
    const int t = threadIdx.x;
    const int wave = t >> 6, lane = t & 63;
    const int quad = lane >> 4, l16 = lane & 15;
    const int m0 = blockIdx.x * 128, o0 = blockIdx.y * 128;
    const int wo = (wave >> 1) * 64, wm = (wave & 1) * 64;
    const int Mplane = 1 << mshift;
    const int r_in = lane >> 2;   // row within a 16-row staging block
    const int cch = lane & 3;     // 16B chunk within a 64B row

    f32x4 acc[4][4] = {};

    const bf16* wbase = W + (size_t)o0 * 1024 + kofs;
    const bf16* xbase = X + (size_t)m0 * K;

    for (int kk = 0; kk < K; kk += 32) {
        #pragma unroll
        for (int i = 0; i < 2; ++i) {
            int rblk = wave * 2 + i;
            int row = rblk * 16 + r_in;
            load16_to_lds(wbase + (size_t)row * 1024 + kk + cch * 8,
                          &Wt[rblk * 512 + lane * 8]);
            load16_to_lds(xbase + (size_t)row * K + kk + cch * 8,
                          &Xt[rblk * 512 + lane * 8]);
        }
        __syncthreads();   // drains vmcnt (global_load_lds) before use
        bf16x8 af[4], bfr[4];
        #pragma unroll
        for (int i = 0; i < 4; ++i)
            af[i] = *(const bf16x8*)&Wt[(wo + i * 16 + l16) * 32 + quad * 8];
        #pragma unroll
        for (int jj = 0; jj < 4; ++jj)
            bfr[jj] = *(const bf16x8*)&Xt[(wm + jj * 16 + l16) * 32 + quad * 8];
        #pragma unroll
        for (int i = 0; i < 4; ++i)
            #pragma unroll
            for (int jj = 0; jj < 4; ++jj)
                acc[i][jj] = __builtin_amdgcn_mfma_f32_16x16x32_bf16(
                    af[i], bfr[jj], acc[i][jj], 0, 0, 0);
        __syncthreads();   // all waves done reading before restage
    }

    // Epilogue. D layout: col(m)=lane&15, row(o)=quad*4+reg  [m89-verified]
    #pragma unroll
    for (int i = 0; i < 4; ++i) {
        int o = o0 + wo + i * 16 + quad * 4;
        #pragma unroll
        for (int jj = 0; jj < 4; ++jj) {
            int m = m0 + wm + jj * 16 + l16;
            int bb = m >> mshift;
            int mp = m & (Mplane - 1);
            bf16* yp = Y + ((size_t)bb * 256 + o) * Mplane + mp;
            #pragma unroll
            for (int r = 0; r < 4; ++r)
                yp[(size_t)r * Mplane] = (bf16)acc[i][jj][r];
        }
    }
}

// ---------------------------------------------------------------------------
// Bilinear 2x upsample of z (per (b,o) 64x64 plane, cached in LDS as fp32),
// y = y1 + up(z).  Weights 0.75/0.25 per axis; edges clamp (== jax renorm).
__device__ __forceinline__ float up_val(const float* zs, int p) {
    int h = p >> 7, w = p & 127;
    int j0 = h >> 1, k0 = w >> 1;
    int jn = (h & 1) ? min(j0 + 1, 63) : max(j0 - 1, 0);
    int kn = (w & 1) ? min(k0 + 1, 63) : max(k0 - 1, 0);
    float zmm = zs[j0 * 64 + k0], zmn = zs[j0 * 64 + kn];
    float znm = zs[jn * 64 + k0], znn = zs[jn * 64 + kn];
    return 0.5625f * zmm + 0.1875f * (zmn + znm) + 0.0625f * znn;
}

__device__ __forceinline__ void load_zplane(const bf16* zp, float* zs, int t) {
    for (int i = 0; i < 2; ++i) {
        int idx = (i * 256 + t) * 8;
        bf16x8 v = *(const bf16x8*)(zp + idx);
        #pragma unroll
        for (int e = 0; e < 8; ++e) zs[idx + e] = (float)v[e];
    }
}

__global__ __launch_bounds__(256) void stats_k(const bf16* __restrict__ y1,
                                               const bf16* __restrict__ z,
                                               float* __restrict__ stats) {
    __shared__ float zs[4096];
    __shared__ float red[8];
    const int bid = blockIdx.x;               // grid 2048 = b*256 + o
    const int o = bid & 255, b = bid >> 8;
    const int t = threadIdx.x;
    const bf16* zp = z + ((size_t)b * 256 + o) * 4096;
    const bf16* yp = y1 + ((size_t)b * 256 + o) * 16384;
    load_zplane(zp, zs, t);
    __syncthreads();
    float s = 0.f, ss = 0.f;
    for (int i = 0; i < 64; ++i) {
        int p = i * 256 + t;
        float y = (float)yp[p] + up_val(zs, p);
        s += y; ss += y * y;
    }
    #pragma unroll
    for (int off = 32; off > 0; off >>= 1) {
        s += __shfl_down(s, off);
        ss += __shfl_down(ss, off);
    }
    if ((t & 63) == 0) { red[t >> 6] = s; red[4 + (t >> 6)] = ss; }
    __syncthreads();
    if (t == 0) {
        atomicAdd(&stats[o],       red[0] + red[1] + red[2] + red[3]);
        atomicAdd(&stats[256 + o], red[4] + red[5] + red[6] + red[7]);
    }
}

__global__ __launch_bounds__(256) void finalize_k(float* __restrict__ stats,
                                                  const float* __restrict__ gamma,
                                                  const float* __restrict__ beta) {
    int o = threadIdx.x;                       // 1 block, 256 threads
    const float n = 131072.f;
    float mean = stats[o] / n;
    float var = stats[256 + o] / n - mean * mean;
    float rstd = rsqrtf(var + 1e-5f);
    float sc = rstd * gamma[o];
    stats[512 + o] = sc;
    stats[768 + o] = beta[o] - mean * sc;
}

__global__ __launch_bounds__(256) void apply_k(const bf16* __restrict__ y1,
                                               const bf16* __restrict__ z,
                                               const float* __restrict__ stats,
                                               float* __restrict__ out) {
    __shared__ float zs[4096];
    const int bid = blockIdx.x;
    const int o = bid & 255, b = bid >> 8;
    const int t = threadIdx.x;
    const bf16* zp = z + ((size_t)b * 256 + o) * 4096;
    const bf16* yp = y1 + ((size_t)b * 256 + o) * 16384;
    float* op = out + ((size_t)b * 256 + o) * 16384;
    const float sc = stats[512 + o], sh = stats[768 + o];
    load_zplane(zp, zs, t);
    __syncthreads();
    for (int i = 0; i < 64; ++i) {
        int p = i * 256 + t;
        float y = (float)yp[p] + up_val(zs, p);
        op[p] = fmaxf(fmaf(y, sc, sh), 0.f);
    }
}

// ---------------------------------------------------------------------------
extern "C" void kernel_launch(void* const* d_in, const int* in_sizes, int n_in,
                              void* d_out, int out_size, void* d_ws, size_t ws_size,
                              hipStream_t stream) {
    const float* x      = (const float*)d_in[0];   // (8,256,128,128)
    const float* conv_w = (const float*)d_in[1];   // (256,1024)
    const float* gamma  = (const float*)d_in[2];   // (256,)
    const float* beta   = (const float*)d_in[3];   // (256,)
    float* out = (float*)d_out;

    char* ws = (char*)d_ws;
    // layout: Wbf 512KB | x_t 64MB | z 16MB | stats 4KB | shared(cT then y1) 64MB
    bf16*  Wbf   = (bf16*)ws;
    bf16*  xt    = (bf16*)(ws + (512ll << 10));
    bf16*  z     = (bf16*)(ws + (512ll << 10) + (64ll << 20));
    float* stats = (float*)(ws + (512ll << 10) + (80ll << 20));
    bf16*  shared_reg = (bf16*)(ws + (512ll << 10) + (80ll << 20) + 4096);
    bf16*  cT = shared_reg;   // 48MB, dead after GEMM2
    bf16*  y1 = shared_reg;   // 64MB, written by GEMM1 after GEMM2 reads cT

    hipMemsetAsync(stats, 0, 4096, stream);
    prep_w<<<1024, 256, 0, stream>>>(conv_w, Wbf);
    pass0<<<2048, 256, 0, stream>>>(x, xt, cT);
    // GEMM2: z[o][coarse m] over K=768 Haar channels (coarse grid)
    gemm_bt<<<dim3(256, 2), 256, 0, stream>>>(Wbf, cT, z, 768, 256, 12);
    // GEMM1: y1[o][fine m] over K=256 raw channels
    gemm_bt<<<dim3(1024, 2), 256, 0, stream>>>(Wbf, xt, y1, 256, 0, 14);
    stats_k<<<2048, 256, 0, stream>>>(y1, z, stats);
    finalize_k<<<1, 256, 0, stream>>>(stats, gamma, beta);
    apply_k<<<2048, 256, 0, stream>>>(y1, z, stats, out);
}

// Round 2
// 351.997 us; speedup vs baseline: 1.0035x; 1.0035x over previous
//
#include <hip/hip_runtime.h>
#include <hip/hip_bf16.h>

typedef __bf16 bf16;
typedef __bf16 bf16x4 __attribute__((ext_vector_type(4)));
typedef __bf16 bf16x8 __attribute__((ext_vector_type(8)));
typedef float  f32x4  __attribute__((ext_vector_type(4)));

#define AS1 __attribute__((address_space(1)))
#define AS3 __attribute__((address_space(3)))

// 16B async global->LDS. LDS dest is wave-uniform base + lane*16.
__device__ __forceinline__ void load16_to_lds(const bf16* g, bf16* l) {
    __builtin_amdgcn_global_load_lds((const AS1 unsigned int*)g,
                                     (AS3 unsigned int*)l, 16, 0, 0);
}

// ---------------------------------------------------------------------------
// pass0: blocks 0..2047: read x fp32 once ->
//   xt bf16 [m = b*16384+h*128+w][c]          (GEMM1 B-operand, row-major K)
//   cT bf16 [mc = b*4096+j*64+k][d*256+c]     (GEMM2 B-operand)
// blocks 2048..2303: conv_w fp32 -> bf16 (prep_w folded in).
__global__ __launch_bounds__(256) void pass0(const float* __restrict__ x,
                                             const float* __restrict__ cw,
                                             bf16* __restrict__ wb,
                                             bf16* __restrict__ xt,
                                             bf16* __restrict__ cT) {
    __shared__ bf16 tile[64 * 264];           // [pos = delta*32 + w][c], pad 264
    const int bid = blockIdx.x;
    const int t = threadIdx.x;
    if (bid >= 2048) {                        // W convert: 256 blocks
        int idx = ((bid - 2048) * 256 + t) * 4;
        const float4 v = *(const float4*)(cw + idx);
        bf16x4 o; o[0]=(bf16)v.x; o[1]=(bf16)v.y; o[2]=(bf16)v.z; o[3]=(bf16)v.w;
        *(bf16x4*)(wb + idx) = o;
        return;
    }
    const int wt = bid & 3, j = (bid >> 2) & 63, b = bid >> 8;
    const int w0 = wt * 32;

    // load 256c x 2rows x 32w fp32 -> bf16 LDS (transposed to [pos][c])
    for (int i = 0; i < 16; ++i) {
        int g = i * 256 + t;                  // 4096 float4 chunks
        int c = g >> 4;
        int rem = g & 15;
        int dlt = rem >> 3, w4 = rem & 7;
        const float4 v = *(const float4*)(x +
            ((((size_t)b * 256 + c) * 128 + (2 * j + dlt)) * 128 + w0 + w4 * 4));
        int pos = dlt * 32 + w4 * 4;
        tile[(pos + 0) * 264 + c] = (bf16)v.x;
        tile[(pos + 1) * 264 + c] = (bf16)v.y;
        tile[(pos + 2) * 264 + c] = (bf16)v.z;
        tile[(pos + 3) * 264 + c] = (bf16)v.w;
    }
    __syncthreads();

    // x_t: 64 pos * 32 chunks of 16B, lanes along c -> contiguous 512B stores
    for (int i = 0; i < 8; ++i) {
        int q = i * 256 + t;
        int cq = q & 31, pos = q >> 5;
        int dlt = pos >> 5, w = pos & 31;
        bf16x8 v = *(const bf16x8*)&tile[pos * 264 + cq * 8];
        int h = 2 * j + dlt, wg = w0 + w;
        *(bf16x8*)(xt + (((size_t)b * 16384 + h * 128 + wg) * 256 + cq * 8)) = v;
    }

    // Haar: 16 coarse cols * 32 c-chunks
    for (int i = 0; i < 2; ++i) {
        int q = i * 256 + t;
        int cq = q & 31, kc = q >> 5;
        bf16x8 vp = *(const bf16x8*)&tile[(2 * kc) * 264 + cq * 8];
        bf16x8 vq = *(const bf16x8*)&tile[(2 * kc + 1) * 264 + cq * 8];
        bf16x8 vr = *(const bf16x8*)&tile[(32 + 2 * kc) * 264 + cq * 8];
        bf16x8 vs = *(const bf16x8*)&tile[(33 + 2 * kc) * 264 + cq * 8];
        bf16x8 oh, ov, od;
        #pragma unroll
        for (int e = 0; e < 8; ++e) {
            float p = (float)vp[e], qq = (float)vq[e];
            float r = (float)vr[e], s = (float)vs[e];
            oh[e] = (bf16)(0.5f * (p + qq - r - s));
            ov[e] = (bf16)(0.5f * (p - qq + r - s));
            od[e] = (bf16)(0.5f * (p - qq - r + s));
        }
        size_t row = ((size_t)b * 4096 + j * 64 + wt * 16 + kc) * 768;
        *(bf16x8*)(cT + row + 0 * 256 + cq * 8) = oh;
        *(bf16x8*)(cT + row + 1 * 256 + cq * 8) = ov;
        *(bf16x8*)(cT + row + 2 * 256 + cq * 8) = od;
    }
}

// ---------------------------------------------------------------------------
// gemm_all: one launch, 2560 blocks.
//   blocks 0..511    : z[o][mc]  = W[:,256:1024] . cT   (K=768, coarse grid)
//   blocks 512..2559 : y1[o][m]  = W[:,0:256]    . xt   (K=256, fine grid)
// m97-style: 128x128 tile, BK=32, 4 waves each 64(o)x64(m), global_load_lds.
// MFMA operand order: A=X(m rows), B=W(o rows) => D.row=m (quad*4+reg),
// D.col=o (lane&15) -> per-lane 4 consecutive m at fixed o -> bf16x4 stores.
__global__ __launch_bounds__(256) void gemm_all(const bf16* __restrict__ W,
                                                const bf16* __restrict__ cT,
                                                const bf16* __restrict__ xt,
                                                bf16* __restrict__ z,
                                                bf16* __restrict__ y1) {
    __shared__ bf16 Wt[128 * 32];
    __shared__ bf16 Xt[128 * 32];
    const int bid = blockIdx.x;
    const bf16* X; bf16* Y; int K, kofs, mshift, m0, o0;
    if (bid < 512) {
        K = 768; kofs = 256; mshift = 12; X = cT; Y = z;
        m0 = (bid & 255) * 128; o0 = (bid >> 8) * 128;
    } else {
        int b1 = bid - 512;
        K = 256; kofs = 0; mshift = 14; X = xt; Y = y1;
        m0 = (b1 & 1023) * 128; o0 = (b1 >> 10) * 128;
    }
    const int t = threadIdx.x;
    const int wave = t >> 6, lane = t & 63;
    const int quad = lane >> 4, l16 = lane & 15;
    const int wo = (wave >> 1) * 64, wm = (wave & 1) * 64;
    const int Mplane = 1 << mshift;
    const int r_in = lane >> 2;   // row within a 16-row staging block
    const int cch = lane & 3;     // 16B chunk within a 64B row

    f32x4 acc[4][4] = {};

    const bf16* wbase = W + (size_t)o0 * 1024 + kofs;
    const bf16* xbase = X + (size_t)m0 * K;

    for (int kk = 0; kk < K; kk += 32) {
        #pragma unroll
        for (int i = 0; i < 2; ++i) {
            int rblk = wave * 2 + i;
            int row = rblk * 16 + r_in;
            load16_to_lds(wbase + (size_t)row * 1024 + kk + cch * 8,
                          &Wt[rblk * 512 + lane * 8]);
            load16_to_lds(xbase + (size_t)row * K + kk + cch * 8,
                          &Xt[rblk * 512 + lane * 8]);
        }
        __syncthreads();
        bf16x8 af[4], bfr[4];
        #pragma unroll
        for (int i = 0; i < 4; ++i)
            af[i] = *(const bf16x8*)&Wt[(wo + i * 16 + l16) * 32 + quad * 8];
        #pragma unroll
        for (int jj = 0; jj < 4; ++jj)
            bfr[jj] = *(const bf16x8*)&Xt[(wm + jj * 16 + l16) * 32 + quad * 8];
        #pragma unroll
        for (int i = 0; i < 4; ++i)
            #pragma unroll
            for (int jj = 0; jj < 4; ++jj)
                acc[i][jj] = __builtin_amdgcn_mfma_f32_16x16x32_bf16(
                    bfr[jj], af[i], acc[i][jj], 0, 0, 0);
        __syncthreads();
    }

    // Epilogue: lane holds m = wm+jj*16+quad*4+r (r=reg), o = wo+i*16+l16.
    #pragma unroll
    for (int i = 0; i < 4; ++i) {
        int o = o0 + wo + i * 16 + l16;
        #pragma unroll
        for (int jj = 0; jj < 4; ++jj) {
            int m = m0 + wm + jj * 16 + quad * 4;
            int bb = m >> mshift;
            int mp = m & (Mplane - 1);
            bf16x4 v;
            #pragma unroll
            for (int r = 0; r < 4; ++r) v[r] = (bf16)acc[i][jj][r];
            *(bf16x4*)(Y + ((size_t)bb * 256 + o) * Mplane + mp) = v;
        }
    }
}

// ---------------------------------------------------------------------------
// Bilinear 2x upsample weights: 0.75/0.25 per axis, edge-clamped (== jax).
// z plane cached in LDS fp32 with rows padded to 65 (bank-conflict-free).
__device__ __forceinline__ void load_zplane(const bf16* zp, float* zs, int t) {
    for (int i = 0; i < 2; ++i) {
        int idx = (i * 256 + t) * 8;
        int j = idx >> 6, k = idx & 63;
        bf16x8 v = *(const bf16x8*)(zp + idx);
        #pragma unroll
        for (int e = 0; e < 8; ++e) zs[j * 65 + k + e] = (float)v[e];
    }
}

// Process 8 consecutive w per thread: 12 LDS reads per 8 outputs.
__device__ __forceinline__ void up8(const float* zs, int base, float* u) {
    int h = base >> 7, w0 = base & 127;
    int j0 = h >> 1;
    int jn = (h & 1) ? min(j0 + 1, 63) : max(j0 - 1, 0);
    int K = w0 >> 1;
    float z0[6], z1[6];
    #pragma unroll
    for (int d = 0; d < 6; ++d) {
        int kc = min(max(K - 1 + d, 0), 63);
        z0[d] = zs[j0 * 65 + kc];
        z1[d] = zs[jn * 65 + kc];
    }
    #pragma unroll
    for (int e = 0; e < 8; ++e) {
        int a = (e >> 1) + 1;
        int bb = (e & 1) ? a + 1 : a - 1;
        u[e] = 0.5625f * z0[a] + 0.1875f * (z0[bb] + z1[a]) + 0.0625f * z1[bb];
    }
}

__global__ __launch_bounds__(256) void stats_k(const bf16* __restrict__ y1,
                                               const bf16* __restrict__ z,
                                               float* __restrict__ stats) {
    __shared__ float zs[64 * 65];
    __shared__ float red[8];
    const int bid = blockIdx.x;               // grid 2048 = b*256 + o
    const int o = bid & 255, b = bid >> 8;
    const int t = threadIdx.x;
    const bf16* zp = z + ((size_t)b * 256 + o) * 4096;
    const bf16* yp = y1 + ((size_t)b * 256 + o) * 16384;
    load_zplane(zp, zs, t);
    __syncthreads();
    float s = 0.f, ss = 0.f;
    for (int i = 0; i < 8; ++i) {
        int base = (i * 256 + t) * 8;
        float u[8];
        up8(zs, base, u);
        bf16x8 yv = *(const bf16x8*)(yp + base);
        #pragma unroll
        for (int e = 0; e < 8; ++e) {
            float y = (float)yv[e] + u[e];
            s += y; ss += y * y;
        }
    }
    #pragma unroll
    for (int off = 32; off > 0; off >>= 1) {
        s += __shfl_down(s, off);
        ss += __shfl_down(ss, off);
    }
    if ((t & 63) == 0) { red[t >> 6] = s; red[4 + (t >> 6)] = ss; }
    __syncthreads();
    if (t == 0) {
        atomicAdd(&stats[o],       red[0] + red[1] + red[2] + red[3]);
        atomicAdd(&stats[256 + o], red[4] + red[5] + red[6] + red[7]);
    }
}

__global__ __launch_bounds__(256) void finalize_k(float* __restrict__ stats,
                                                  const float* __restrict__ gamma,
                                                  const float* __restrict__ beta) {
    int o = threadIdx.x;                       // 1 block, 256 threads
    const float n = 131072.f;
    float mean = stats[o] / n;
    float var = stats[256 + o] / n - mean * mean;
    float rstd = rsqrtf(var + 1e-5f);
    float sc = rstd * gamma[o];
    stats[512 + o] = sc;
    stats[768 + o] = beta[o] - mean * sc;
}

__global__ __launch_bounds__(256) void apply_k(const bf16* __restrict__ y1,
                                               const bf16* __restrict__ z,
                                               const float* __restrict__ stats,
                                               float* __restrict__ out) {
    __shared__ float zs[64 * 65];
    const int bid = blockIdx.x;
    const int o = bid & 255, b = bid >> 8;
    const int t = threadIdx.x;
    const bf16* zp = z + ((size_t)b * 256 + o) * 4096;
    const bf16* yp = y1 + ((size_t)b * 256 + o) * 16384;
    float* op = out + ((size_t)b * 256 + o) * 16384;
    const float sc = stats[512 + o], sh = stats[768 + o];
    load_zplane(zp, zs, t);
    __syncthreads();
    for (int i = 0; i < 8; ++i) {
        int base = (i * 256 + t) * 8;
        float u[8];
        up8(zs, base, u);
        bf16x8 yv = *(const bf16x8*)(yp + base);
        float4 o0, o1;
        o0.x = fmaxf(fmaf((float)yv[0] + u[0], sc, sh), 0.f);
        o0.y = fmaxf(fmaf((float)yv[1] + u[1], sc, sh), 0.f);
        o0.z = fmaxf(fmaf((float)yv[2] + u[2], sc, sh), 0.f);
        o0.w = fmaxf(fmaf((float)yv[3] + u[3], sc, sh), 0.f);
        o1.x = fmaxf(fmaf((float)yv[4] + u[4], sc, sh), 0.f);
        o1.y = fmaxf(fmaf((float)yv[5] + u[5], sc, sh), 0.f);
        o1.z = fmaxf(fmaf((float)yv[6] + u[6], sc, sh), 0.f);
        o1.w = fmaxf(fmaf((float)yv[7] + u[7], sc, sh), 0.f);
        *(float4*)(op + base) = o0;
        *(float4*)(op + base + 4) = o1;
    }
}

// ---------------------------------------------------------------------------
extern "C" void kernel_launch(void* const* d_in, const int* in_sizes, int n_in,
                              void* d_out, int out_size, void* d_ws, size_t ws_size,
                              hipStream_t stream) {
    const float* x      = (const float*)d_in[0];   // (8,256,128,128)
    const float* conv_w = (const float*)d_in[1];   // (256,1024)
    const float* gamma  = (const float*)d_in[2];   // (256,)
    const float* beta   = (const float*)d_in[3];   // (256,)
    float* out = (float*)d_out;

    char* ws = (char*)d_ws;
    // Wbf 512K | xt 64M | z 16M | stats 4K | cT 48M | y1 64M  (~193 MB total)
    // cT and y1 must NOT alias: gemm_all runs both GEMMs concurrently.
    bf16*  Wbf   = (bf16*)ws;
    bf16*  xt    = (bf16*)(ws + (512ll << 10));
    bf16*  z     = (bf16*)(ws + (512ll << 10) + (64ll << 20));
    float* stats = (float*)(ws + (512ll << 10) + (80ll << 20));
    bf16*  cT    = (bf16*)(ws + (512ll << 10) + (80ll << 20) + 4096);
    bf16*  y1    = (bf16*)(ws + (512ll << 10) + (128ll << 20) + 4096);

    hipMemsetAsync(stats, 0, 4096, stream);
    pass0<<<2304, 256, 0, stream>>>(x, conv_w, Wbf, xt, cT);
    gemm_all<<<2560, 256, 0, stream>>>(Wbf, cT, xt, z, y1);
    stats_k<<<2048, 256, 0, stream>>>(y1, z, stats);
    finalize_k<<<1, 256, 0, stream>>>(stats, gamma, beta);
    apply_k<<<2048, 256, 0, stream>>>(y1, z, stats, out);
}